// Round 1
// baseline (2613.961 us; speedup 1.0000x reference)
//
#include <hip/hip_runtime.h>
#include <hip/hip_bf16.h>

// sLSTM fused cell: B=D=4096.
// pre_g = [x, h^T] @ [w_g; u_g]  (M=4096, N=4096, K=8192), 4 gates -> 1.1 TFLOP
// Strategy: cast/transpose everything to bf16 (A row-major MxK, W as B^T NxK),
// m97-style 128x128x32 MFMA GEMM with global_load_lds(16B), fp32 epilogue.

#define DD 4096
#define BB 4096
#define KK 8192   // 2*DD

typedef __hip_bfloat16 bf16;
typedef __attribute__((ext_vector_type(8))) short short8;
typedef __attribute__((ext_vector_type(4))) float f32x4;

__device__ __forceinline__ void gld_lds16(const bf16* g, bf16* l) {
    __builtin_amdgcn_global_load_lds(
        (const __attribute__((address_space(1))) void*)g,
        (__attribute__((address_space(3))) void*)l,
        16, 0, 0);
}

// ---- cast x (4096x4096 f32, row-major) into Ahat[b][0..4095], row stride KK ----
__global__ __launch_bounds__(256) void cast_x(const float* __restrict__ x,
                                              bf16* __restrict__ A) {
    long base = ((long)blockIdx.x * 256 + threadIdx.x) * 4;
    int b = (int)(base >> 12);
    int k = (int)(base & 4095);
    float4 v = *(const float4*)(x + base);
    bf16 tmp[4];
    tmp[0] = __float2bfloat16(v.x);
    tmp[1] = __float2bfloat16(v.y);
    tmp[2] = __float2bfloat16(v.z);
    tmp[3] = __float2bfloat16(v.w);
    bf16* o = A + (long)b * KK + k;
    *(uint2*)o = *(uint2*)tmp;  // 8B store, aligned (k%4==0)
}

// ---- transpose-cast: out[c * KK + outOff + r] = bf16(in[r * 4096 + c]) ----
// in is 4096x4096 f32 row-major. Used for h (->Ahat cols 4096..) and all weights.
__global__ __launch_bounds__(256) void transpose_cast(const float* __restrict__ in,
                                                      bf16* __restrict__ out,
                                                      long outOff) {
    __shared__ float tile[32][33];
    int r0 = blockIdx.y * 32;
    int c0 = blockIdx.x * 32;
    int tx = threadIdx.x;  // 0..31
    int ty = threadIdx.y;  // 0..7
    #pragma unroll
    for (int i = 0; i < 4; i++) {
        int r = r0 + ty + i * 8;
        tile[ty + i * 8][tx] = in[(long)r * 4096 + c0 + tx];
    }
    __syncthreads();
    #pragma unroll
    for (int i = 0; i < 4; i++) {
        int c = c0 + ty + i * 8;
        out[(long)c * KK + outOff + r0 + tx] = __float2bfloat16(tile[tx][ty + i * 8]);
    }
}

// ---- GEMM: C[g] (4096x4096 f32) = A (4096xKK bf16) @ Bt[g]^T (Bt: 4096xKK bf16) ----
__global__ __launch_bounds__(256) void gemm_bt(const bf16* __restrict__ A,
                                               const bf16* __restrict__ Bt,
                                               float* __restrict__ C) {
    __shared__ bf16 Ash[128 * 32];
    __shared__ bf16 Bsh[128 * 32];

    const int m0 = blockIdx.x * 128;   // m fastest: consecutive blocks share Bt panel
    const int n0 = blockIdx.y * 128;
    const int g  = blockIdx.z;

    const bf16* Bg = Bt + (long)g * DD * KK;
    float* Cg = C + (long)g * BB * DD;

    const int tid  = threadIdx.x;
    const int lane = tid & 63;
    const int wv   = tid >> 6;
    const int wm   = wv & 1;
    const int wn   = wv >> 1;
    const int quad = lane >> 4;
    const int fr   = lane & 15;

    // staging: 8 chunks of 1KB per tile; chunk c covers rows 16c..16c+15 (64B rows)
    // lane l -> row 16c + l/4, col byte (l%4)*16 ; HW writes LDS base + l*16
    const int c0 = wv * 2, c1 = wv * 2 + 1;
    const int srow = lane >> 2;
    const int scol = (lane & 3) * 8;
    const bf16* aG0 = A  + (long)(m0 + c0 * 16 + srow) * KK + scol;
    const bf16* aG1 = A  + (long)(m0 + c1 * 16 + srow) * KK + scol;
    const bf16* bG0 = Bg + (long)(n0 + c0 * 16 + srow) * KK + scol;
    const bf16* bG1 = Bg + (long)(n0 + c1 * 16 + srow) * KK + scol;
    bf16* aL0 = &Ash[c0 * 512];
    bf16* aL1 = &Ash[c1 * 512];
    bf16* bL0 = &Bsh[c0 * 512];
    bf16* bL1 = &Bsh[c1 * 512];

    f32x4 acc[4][4];
    #pragma unroll
    for (int i = 0; i < 4; i++)
        #pragma unroll
        for (int j = 0; j < 4; j++)
            acc[i][j] = (f32x4){0.f, 0.f, 0.f, 0.f};

    int aOff[4], bOff[4];
    #pragma unroll
    for (int i = 0; i < 4; i++) {
        aOff[i] = (wm * 64 + i * 16 + fr) * 32 + quad * 8;
        bOff[i] = (wn * 64 + i * 16 + fr) * 32 + quad * 8;
    }

    for (int kt = 0; kt < KK; kt += 32) {
        gld_lds16(aG0 + kt, aL0);
        gld_lds16(aG1 + kt, aL1);
        gld_lds16(bG0 + kt, bL0);
        gld_lds16(bG1 + kt, bL1);
        __syncthreads();   // drains vmcnt (global_load_lds) + lgkm

        short8 af[4], bfv[4];
        #pragma unroll
        for (int i = 0; i < 4; i++) af[i]  = *(const short8*)&Ash[aOff[i]];
        #pragma unroll
        for (int i = 0; i < 4; i++) bfv[i] = *(const short8*)&Bsh[bOff[i]];
        #pragma unroll
        for (int i = 0; i < 4; i++)
            #pragma unroll
            for (int j = 0; j < 4; j++)
                acc[i][j] = __builtin_amdgcn_mfma_f32_16x16x32_bf16(
                    af[i], bfv[j], acc[i][j], 0, 0, 0);
        __syncthreads();
    }

    // C/D layout (m89/m91-verified): col = lane&15, row = quad*4 + reg
    #pragma unroll
    for (int i = 0; i < 4; i++) {
        const int rbase = m0 + wm * 64 + i * 16 + quad * 4;
        #pragma unroll
        for (int j = 0; j < 4; j++) {
            const int col = n0 + wn * 64 + j * 16 + fr;
            #pragma unroll
            for (int p = 0; p < 4; p++)
                Cg[(long)(rbase + p) * DD + col] = acc[i][j][p];
        }
    }
}

// ---- elementwise epilogue: in-place on d_out (pre_i|pre_f|pre_o|pre_c -> h|c|m|n) ----
__global__ __launch_bounds__(256) void epilogue(float* __restrict__ out,
                                                const float* __restrict__ cc,
                                                const float* __restrict__ mm,
                                                const float* __restrict__ nn,
                                                const float* __restrict__ bi,
                                                const float* __restrict__ bff,
                                                const float* __restrict__ bo,
                                                const float* __restrict__ bc) {
    const long S = (long)BB * DD;
    long idx = (long)blockIdx.x * 256 + threadIdx.x;
    int j = (int)(idx & (DD - 1));
    float p_i = out[idx]         + bi[j];
    float p_f = out[S + idx]     + bff[j];
    float p_o = out[2 * S + idx] + bo[j];
    float p_c = out[3 * S + idx] + bc[j];
    float mv = mm[idx], cv = cc[idx], nv = nn[idx];

    float m_new = fmaxf(p_f + mv, p_i);
    float i_p = expf(p_i - p_f > mv ? 0.0f : p_i - m_new);  // == expf(p_i - m_new)
    i_p = expf(p_i - m_new);
    float f_p = expf(p_f);   // faithful to reference: exp(log f + m - m)
    float o_t = 1.0f / (1.0f + expf(-p_o));
    float z_t = tanhf(p_c);
    float c_new = f_p * cv + i_p * z_t;
    float n_new = f_p * nv + i_p;   // n>0, f_p,i_p>0 => n_new>0
    float h_new = o_t * (c_new / n_new);

    out[idx]         = h_new;
    out[S + idx]     = c_new;
    out[2 * S + idx] = m_new;
    out[3 * S + idx] = n_new;
}

extern "C" void kernel_launch(void* const* d_in, const int* in_sizes, int n_in,
                              void* d_out, int out_size, void* d_ws, size_t ws_size,
                              hipStream_t stream) {
    const float* x  = (const float*)d_in[0];
    const float* h  = (const float*)d_in[1];
    const float* c  = (const float*)d_in[2];
    const float* m  = (const float*)d_in[3];
    const float* n  = (const float*)d_in[4];
    const float* W[4] = {(const float*)d_in[5], (const float*)d_in[6],
                         (const float*)d_in[7], (const float*)d_in[8]};
    const float* U[4] = {(const float*)d_in[9], (const float*)d_in[10],
                         (const float*)d_in[11], (const float*)d_in[12]};
    const float* bi = (const float*)d_in[13];
    const float* bf = (const float*)d_in[14];
    const float* bo = (const float*)d_in[15];
    const float* bc = (const float*)d_in[16];
    float* out = (float*)d_out;

    // Workspace layout (bf16): Ahat (BB x KK) then WT[4] (DD x KK each) = 320 MiB
    bf16* Ahat = (bf16*)d_ws;
    bf16* WT   = Ahat + (long)BB * KK;

    // 1) casts/transposes
    cast_x<<<(BB * (long)DD / 4) / 256, 256, 0, stream>>>(x, Ahat);
    dim3 tb(32, 8);
    dim3 tg(128, 128);
    transpose_cast<<<tg, tb, 0, stream>>>(h, Ahat, 4096);  // h^T -> cols 4096..
    for (int g = 0; g < 4; g++) {
        bf16* WTg = WT + (long)g * DD * KK;
        transpose_cast<<<tg, tb, 0, stream>>>(W[g], WTg, 0);
        transpose_cast<<<tg, tb, 0, stream>>>(U[g], WTg, 4096);
    }

    // 2) fused 4-gate GEMM -> pre activations into d_out (as scratch)
    dim3 gg(BB / 128, DD / 128, 4);
    gemm_bt<<<gg, 256, 0, stream>>>(Ahat, WT, out);

    // 3) elementwise sLSTM epilogue, in place
    epilogue<<<(unsigned)(((long)BB * DD) / 256), 256, 0, stream>>>(
        out, c, m, n, bi, bf, bo, bc);
}